// Round 1
// baseline (1430.450 us; speedup 1.0000x reference)
//
#include <hip/hip_runtime.h>

#define SEQ   2048
#define BATCH 2
#define NHQ   32
#define NHKV  8
#define DHEAD 128
#define QSCALE 0.08838834764831845f   // 1/sqrt(128)

typedef short bf16x8 __attribute__((ext_vector_type(8)));
typedef float f32x4  __attribute__((ext_vector_type(4)));

// float -> bf16 bits, round-to-nearest-even
__device__ __forceinline__ short f2bf(float x) {
  union { float f; unsigned u; } c; c.f = x;
  unsigned u = c.u;
  unsigned r = (u + 0x7fffu + ((u >> 16) & 1u)) >> 16;
  return (short)r;
}

// One wave handles a 16-row Q tile; block = 4 independent waves (64 q rows).
// K-loop tiles are 32 keys; QK^T = 8 MFMAs, PV = 8 MFMAs per tile.
// NOTE: no __syncthreads() in the k-loop — waves have different causal trip
// counts; the P layout round-trip uses a wave-private LDS region only.
__global__ __launch_bounds__(256) void attn_fwd(const float* __restrict__ Q,
                                                const float* __restrict__ K,
                                                const float* __restrict__ V,
                                                float* __restrict__ O) {
  const int qt   = blockIdx.x;          // 0..31  (q tile of 64 rows)
  const int bh   = blockIdx.y;          // 0..63  (b*NHQ + hq)
  const int b    = bh >> 5;
  const int hq   = bh & 31;
  const int hkv  = hq >> 2;             // GQA group of 4
  const int wave = threadIdx.x >> 6;
  const int lane = threadIdx.x & 63;
  const int col  = lane & 15;
  const int quad = lane >> 4;

  const int q_base = qt * 64 + wave * 16;

  const int qrs = BATCH * NHQ * DHEAD;   // 8192 floats between q rows
  const int krs = BATCH * NHKV * DHEAD;  // 2048 floats between k/v rows

  const float* Qp = Q + ((size_t)b * NHQ  + hq ) * DHEAD;
  const float* Kp = K + ((size_t)b * NHKV + hkv) * DHEAD;
  const float* Vp = V + ((size_t)b * NHKV + hkv) * DHEAD;
  float*       Op = O + ((size_t)b * NHQ  + hq ) * DHEAD;

  // wave-private P staging: 16 rows x 32 cols bf16, row stride 36 (bank-safe)
  __shared__ short plds[4][16 * 36];
  short* pw = plds[wave];

  // ---- Q fragments, A-operand layout: A[m=col][k = c*32 + quad*8 + j] ----
  bf16x8 qf[4];
  {
    const float* qrow = Qp + (size_t)(q_base + col) * qrs + quad * 8;
    #pragma unroll
    for (int c = 0; c < 4; ++c) {
      const float4* p = (const float4*)(qrow + c * 32);
      float4 a = p[0], bb = p[1];
      qf[c][0] = f2bf(a.x);  qf[c][1] = f2bf(a.y);
      qf[c][2] = f2bf(a.z);  qf[c][3] = f2bf(a.w);
      qf[c][4] = f2bf(bb.x); qf[c][5] = f2bf(bb.y);
      qf[c][6] = f2bf(bb.z); qf[c][7] = f2bf(bb.w);
    }
  }

  f32x4 oacc[8];
  #pragma unroll
  for (int h = 0; h < 8; ++h) oacc[h] = (f32x4){0.f, 0.f, 0.f, 0.f};
  float mrow[4] = {-__builtin_inff(), -__builtin_inff(),
                   -__builtin_inff(), -__builtin_inff()};
  float lrow[4] = {0.f, 0.f, 0.f, 0.f};

  const int nt = (q_base + 15) / 32 + 1;   // causal trip count

  for (int kt = 0; kt < nt; ++kt) {
    const int k0 = kt * 32;

    // ---- K fragments (B-operand for QK^T; same load pattern as A) ----
    bf16x8 kf[2][4];
    #pragma unroll
    for (int t = 0; t < 2; ++t) {
      const float* krow = Kp + (size_t)(k0 + t * 16 + col) * krs + quad * 8;
      #pragma unroll
      for (int c = 0; c < 4; ++c) {
        const float4* p = (const float4*)(krow + c * 32);
        float4 a = p[0], bb = p[1];
        kf[t][c][0] = f2bf(a.x);  kf[t][c][1] = f2bf(a.y);
        kf[t][c][2] = f2bf(a.z);  kf[t][c][3] = f2bf(a.w);
        kf[t][c][4] = f2bf(bb.x); kf[t][c][5] = f2bf(bb.y);
        kf[t][c][6] = f2bf(bb.z); kf[t][c][7] = f2bf(bb.w);
      }
    }

    // ---- V fragments (B-operand for PV): vf[h][j] = V[k0+quad*8+j][h*16+col]
    bf16x8 vf[8];
    #pragma unroll
    for (int j = 0; j < 8; ++j) {
      const float* vrow = Vp + (size_t)(k0 + quad * 8 + j) * krs + col;
      #pragma unroll
      for (int h = 0; h < 8; ++h) vf[h][j] = f2bf(vrow[h * 16]);
    }

    // ---- S = Q K^T (16x32 tile as two 16x16 MFMA n-tiles) ----
    f32x4 s0 = {0.f, 0.f, 0.f, 0.f};
    f32x4 s1 = {0.f, 0.f, 0.f, 0.f};
    #pragma unroll
    for (int c = 0; c < 4; ++c) {
      s0 = __builtin_amdgcn_mfma_f32_16x16x32_bf16(qf[c], kf[0][c], s0, 0, 0, 0);
      s1 = __builtin_amdgcn_mfma_f32_16x16x32_bf16(qf[c], kf[1][c], s1, 0, 0, 0);
    }

    // ---- online softmax (C/D layout: row = quad*4+r, col = lane&15) ----
    const bool last = (kt == nt - 1);
    float p0[4], p1[4], alpha[4];
    #pragma unroll
    for (int r = 0; r < 4; ++r) {
      float x0 = s0[r] * QSCALE;
      float x1 = s1[r] * QSCALE;
      const int qr = q_base + quad * 4 + r;
      if (last) {
        if (k0 + col      > qr) x0 = -__builtin_inff();
        if (k0 + 16 + col > qr) x1 = -__builtin_inff();
      }
      float mx = fmaxf(x0, x1);
      #pragma unroll
      for (int off = 1; off < 16; off <<= 1) mx = fmaxf(mx, __shfl_xor(mx, off));
      const float mnew = fmaxf(mrow[r], mx);
      alpha[r] = __expf(mrow[r] - mnew);   // first iter: exp(-inf)=0
      mrow[r]  = mnew;
      float e0 = __expf(x0 - mnew);
      float e1 = __expf(x1 - mnew);
      p0[r] = e0; p1[r] = e1;
      float rs = e0 + e1;
      #pragma unroll
      for (int off = 1; off < 16; off <<= 1) rs += __shfl_xor(rs, off);
      lrow[r] = lrow[r] * alpha[r] + rs;
    }

    #pragma unroll
    for (int h = 0; h < 8; ++h) {
      #pragma unroll
      for (int r = 0; r < 4; ++r) oacc[h][r] *= alpha[r];
    }

    // ---- P: C/D layout -> LDS -> A-operand layout (wave-private) ----
    #pragma unroll
    for (int r = 0; r < 4; ++r) {
      pw[(quad * 4 + r) * 36 + col]      = f2bf(p0[r]);
      pw[(quad * 4 + r) * 36 + 16 + col] = f2bf(p1[r]);
    }
    __asm__ volatile("s_waitcnt lgkmcnt(0)" ::: "memory");
    bf16x8 pf;
    {
      const short* pr = pw + col * 36 + quad * 8;
      #pragma unroll
      for (int j = 0; j < 8; ++j) pf[j] = pr[j];
    }
    __asm__ volatile("" ::: "memory");

    // ---- O += P V ----
    #pragma unroll
    for (int h = 0; h < 8; ++h)
      oacc[h] = __builtin_amdgcn_mfma_f32_16x16x32_bf16(pf, vf[h], oacc[h], 0, 0, 0);
  }

  // ---- epilogue: normalize and store (O tile in C/D layout) ----
  float inv[4];
  #pragma unroll
  for (int r = 0; r < 4; ++r) inv[r] = 1.0f / lrow[r];
  #pragma unroll
  for (int h = 0; h < 8; ++h) {
    #pragma unroll
    for (int r = 0; r < 4; ++r) {
      Op[(size_t)(q_base + quad * 4 + r) * qrs + h * 16 + col] = oacc[h][r] * inv[r];
    }
  }
}

extern "C" void kernel_launch(void* const* d_in, const int* in_sizes, int n_in,
                              void* d_out, int out_size, void* d_ws, size_t ws_size,
                              hipStream_t stream) {
  const float* Q = (const float*)d_in[0];
  const float* K = (const float*)d_in[1];
  const float* V = (const float*)d_in[2];
  float* O = (float*)d_out;
  (void)in_sizes; (void)n_in; (void)out_size; (void)d_ws; (void)ws_size;
  dim3 grid(SEQ / 64, BATCH * NHQ);
  attn_fwd<<<grid, dim3(256), 0, stream>>>(Q, K, V, O);
}

// Round 3
// 423.236 us; speedup vs baseline: 3.3798x; 3.3798x over previous
//
#include <hip/hip_runtime.h>

#define SEQ    2048
#define BATCH  2
#define NHQ    32
#define NHKV   8
#define DHEAD  128
#define QSCALE 0.08838834764831845f   // 1/sqrt(128)

typedef __fp16 f16;
typedef f16 f16x2 __attribute__((ext_vector_type(2)));
typedef f16 f16x4 __attribute__((ext_vector_type(4)));
typedef f16 f16x8 __attribute__((ext_vector_type(8)));
typedef float f32x4 __attribute__((ext_vector_type(4)));

#define KSTRIDE 136                 // halfs per K-tile row (128 + 8 pad)
#define VSTRIDE 34                  // halfs per Vt row (32 + 2 pad)
#define KBUF    (32 * KSTRIDE)      // 4352 halfs
#define VBUF    (128 * VSTRIDE)     // 4352 halfs
#define EPSTRIDE 132                // floats per epilogue row (128 + 4 pad)

// Dataflow: S^T = K Q^T  (q on lane&15, k on quad*4+reg)  ->  cheap softmax
// (in-register + 2 shuffles)  ->  P^T is ALREADY the B-operand layout of
// mfma_f32_16x16x16f16  ->  O^T = V^T P^T with V^T staged d-major in LDS.
// K/V staged cooperatively by the whole block, double-buffered, 1 barrier/tile.
__global__ __launch_bounds__(256, 4) void attn_fwd(const float* __restrict__ Q,
                                                   const float* __restrict__ K,
                                                   const float* __restrict__ V,
                                                   float* __restrict__ O) {
  const int qt  = gridDim.x - 1 - blockIdx.x;   // heavy (large-qt) blocks first
  const int bh  = blockIdx.y;
  const int b   = bh >> 5;
  const int hq  = bh & 31;
  const int hkv = hq >> 2;
  const int t    = threadIdx.x;
  const int wave = t >> 6;
  const int lane = t & 63;
  const int col  = lane & 15;
  const int quad = lane >> 4;

  const int q_base = qt * 64 + wave * 16;
  const int qrs = BATCH * NHQ * DHEAD;    // 8192
  const int krs = BATCH * NHKV * DHEAD;   // 2048

  const float* Qp = Q + ((size_t)b * NHQ  + hq ) * DHEAD;
  const float* Kp = K + ((size_t)b * NHKV + hkv) * DHEAD;
  const float* Vp = V + ((size_t)b * NHKV + hkv) * DHEAD;
  float*       Op = O + ((size_t)b * NHQ  + hq ) * DHEAD;

  __shared__ __align__(16) f16 smem[2 * KBUF + 2 * VBUF];  // 34816 B

  // ---- Q fragments (B-operand of 16x16x32: B[n=lane&15][k=quad*8+j]),
  //      pre-scaled by 1/sqrt(D) ----
  f16x8 qf[4];
  {
    const float* qsrc = Qp + (size_t)(q_base + col) * qrs + quad * 8;
    #pragma unroll
    for (int c = 0; c < 4; ++c) {
      float4 a = *(const float4*)(qsrc + c * 32);
      float4 e = *(const float4*)(qsrc + c * 32 + 4);
      f16x2 p0 = __builtin_amdgcn_cvt_pkrtz(a.x * QSCALE, a.y * QSCALE);
      f16x2 p1 = __builtin_amdgcn_cvt_pkrtz(a.z * QSCALE, a.w * QSCALE);
      f16x2 p2 = __builtin_amdgcn_cvt_pkrtz(e.x * QSCALE, e.y * QSCALE);
      f16x2 p3 = __builtin_amdgcn_cvt_pkrtz(e.z * QSCALE, e.w * QSCALE);
      qf[c][0] = p0[0]; qf[c][1] = p0[1]; qf[c][2] = p1[0]; qf[c][3] = p1[1];
      qf[c][4] = p2[0]; qf[c][5] = p2[1]; qf[c][6] = p3[0]; qf[c][7] = p3[1];
    }
  }

  f32x4 oacc[8];
  #pragma unroll
  for (int h = 0; h < 8; ++h) oacc[h] = (f32x4){0.f, 0.f, 0.f, 0.f};
  float m_i = -__builtin_inff();
  float l_i = 0.f;

  const int nt_blk = 2 * qt + 2;                 // block-uniform trip count
  const int nt_w   = ((q_base + 15) >> 5) + 1;   // this wave's causal tiles

  // staging coords: K rows via float4, V rows via float2 (transposed write)
  const int ktk = t >> 5, ktd = (t & 31) * 4;
  const int vtk = t >> 6, vtd = (t & 63) * 2;

  float4 kr[4];
  float2 vr2[8];

  // prologue: global loads for tile 0
  #pragma unroll
  for (int ro = 0; ro < 4; ++ro)
    kr[ro] = *(const float4*)(Kp + (size_t)(ktk + ro * 8) * krs + ktd);
  #pragma unroll
  for (int ro = 0; ro < 8; ++ro)
    vr2[ro] = *(const float2*)(Vp + (size_t)(vtk + ro * 4) * krs + vtd);

  for (int kt = 0; kt < nt_blk; ++kt) {
    const int bf = kt & 1;
    f16* kb = smem + bf * KBUF;
    f16* vb = smem + 2 * KBUF + bf * VBUF;

    // ---- stage tile kt from registers (cvt + LDS write) ----
    #pragma unroll
    for (int ro = 0; ro < 4; ++ro) {
      f16x2 lo = __builtin_amdgcn_cvt_pkrtz(kr[ro].x, kr[ro].y);
      f16x2 hi = __builtin_amdgcn_cvt_pkrtz(kr[ro].z, kr[ro].w);
      f16x4 v4; v4[0] = lo[0]; v4[1] = lo[1]; v4[2] = hi[0]; v4[3] = hi[1];
      *(f16x4*)(kb + (ktk + ro * 8) * KSTRIDE + ktd) = v4;
    }
    #pragma unroll
    for (int ro = 0; ro < 8; ++ro) {   // transposed: Vt[d][k]
      vb[(vtd    ) * VSTRIDE + vtk + ro * 4] = (f16)vr2[ro].x;
      vb[(vtd + 1) * VSTRIDE + vtk + ro * 4] = (f16)vr2[ro].y;
    }

    // ---- issue next tile's global loads (latency hides under compute) ----
    if (kt + 1 < nt_blk) {
      const int k0n = (kt + 1) * 32;
      #pragma unroll
      for (int ro = 0; ro < 4; ++ro)
        kr[ro] = *(const float4*)(Kp + (size_t)(k0n + ktk + ro * 8) * krs + ktd);
      #pragma unroll
      for (int ro = 0; ro < 8; ++ro)
        vr2[ro] = *(const float2*)(Vp + (size_t)(k0n + vtk + ro * 4) * krs + vtd);
    }

    __syncthreads();

    if (kt < nt_w) {
      const int k0 = kt * 32;

      // ---- S^T = K Q^T : A = K rows (m=k), B = Q (n=q) ----
      f32x4 s0 = {0.f, 0.f, 0.f, 0.f}, s1 = {0.f, 0.f, 0.f, 0.f};
      #pragma unroll
      for (int c = 0; c < 4; ++c) {
        f16x8 ka = *(const f16x8*)(kb + col * KSTRIDE + quad * 8 + c * 32);
        s0 = __builtin_amdgcn_mfma_f32_16x16x32_f16(ka, qf[c], s0, 0, 0, 0);
      }
      #pragma unroll
      for (int c = 0; c < 4; ++c) {
        f16x8 ka = *(const f16x8*)(kb + (16 + col) * KSTRIDE + quad * 8 + c * 32);
        s1 = __builtin_amdgcn_mfma_f32_16x16x32_f16(ka, qf[c], s1, 0, 0, 0);
      }

      // ---- causal mask (only final 1-2 tiles); q = col, k = quad*4+r ----
      const int qrow = q_base + col;
      if (k0 + 31 > q_base) {
        #pragma unroll
        for (int r = 0; r < 4; ++r) {
          if (k0 + quad * 4 + r      > qrow) s0[r] = -__builtin_inff();
          if (k0 + 16 + quad * 4 + r > qrow) s1[r] = -__builtin_inff();
        }
      }

      // ---- online softmax: in-register reduce + 2 shuffles ----
      float mx = fmaxf(fmaxf(fmaxf(s0[0], s0[1]), fmaxf(s0[2], s0[3])),
                       fmaxf(fmaxf(s1[0], s1[1]), fmaxf(s1[2], s1[3])));
      mx = fmaxf(mx, __shfl_xor(mx, 16, 64));
      mx = fmaxf(mx, __shfl_xor(mx, 32, 64));
      const float mnew  = fmaxf(m_i, mx);
      const float alpha = __expf(m_i - mnew);   // first tile: exp(-inf)=0
      m_i = mnew;

      float e0[4], e1[4], rs = 0.f;
      #pragma unroll
      for (int r = 0; r < 4; ++r) {
        e0[r] = __expf(s0[r] - mnew);
        e1[r] = __expf(s1[r] - mnew);
        rs += e0[r] + e1[r];
      }
      rs += __shfl_xor(rs, 16, 64);
      rs += __shfl_xor(rs, 32, 64);
      l_i = l_i * alpha + rs;

      #pragma unroll
      for (int h = 0; h < 8; ++h) {
        oacc[h][0] *= alpha; oacc[h][1] *= alpha;
        oacc[h][2] *= alpha; oacc[h][3] *= alpha;
      }

      // ---- P^T already in 16x16x16 B-operand layout ----
      f16x2 a01 = __builtin_amdgcn_cvt_pkrtz(e0[0], e0[1]);
      f16x2 a23 = __builtin_amdgcn_cvt_pkrtz(e0[2], e0[3]);
      f16x2 b01 = __builtin_amdgcn_cvt_pkrtz(e1[0], e1[1]);
      f16x2 b23 = __builtin_amdgcn_cvt_pkrtz(e1[2], e1[3]);
      f16x4 pb0; pb0[0] = a01[0]; pb0[1] = a01[1]; pb0[2] = a23[0]; pb0[3] = a23[1];
      f16x4 pb1; pb1[0] = b01[0]; pb1[1] = b01[1]; pb1[2] = b23[0]; pb1[3] = b23[1];

      // ---- O^T += V^T P^T  (A = V^T rows from Vt LDS) ----
      #pragma unroll
      for (int h = 0; h < 8; ++h) {
        const f16* vr = vb + (h * 16 + col) * VSTRIDE + quad * 4;
        f16x2 x0 = *(const f16x2*)(vr);
        f16x2 x1 = *(const f16x2*)(vr + 2);
        f16x2 y0 = *(const f16x2*)(vr + 16);
        f16x2 y1 = *(const f16x2*)(vr + 18);
        f16x4 va0; va0[0] = x0[0]; va0[1] = x0[1]; va0[2] = x1[0]; va0[3] = x1[1];
        f16x4 va1; va1[0] = y0[0]; va1[1] = y0[1]; va1[2] = y1[0]; va1[3] = y1[1];
        oacc[h] = __builtin_amdgcn_mfma_f32_16x16x16f16(va0, pb0, oacc[h], 0, 0, 0);
        oacc[h] = __builtin_amdgcn_mfma_f32_16x16x16f16(va1, pb1, oacc[h], 0, 0, 0);
      }
    }
  }

  __syncthreads();   // K/V LDS no longer needed; reuse for epilogue transpose

  {
    float* ep = (float*)smem + wave * (16 * EPSTRIDE);   // wave-private 8448 B
    const float invl = 1.0f / l_i;
    #pragma unroll
    for (int h = 0; h < 8; ++h) {
      f32x4 v = oacc[h];
      v[0] *= invl; v[1] *= invl; v[2] *= invl; v[3] *= invl;
      *(f32x4*)(ep + col * EPSTRIDE + h * 16 + quad * 4) = v;
    }
    __asm__ volatile("s_waitcnt lgkmcnt(0)" ::: "memory");  // wave-private only
    const int row = lane >> 2;
    const int d4  = lane & 3;
    #pragma unroll
    for (int c = 0; c < 8; ++c) {
      const int f = d4 + c * 4;
      float4 o = *(const float4*)(ep + row * EPSTRIDE + f * 4);
      *(float4*)(Op + (size_t)(q_base + row) * qrs + f * 4) = o;
    }
  }
}

extern "C" void kernel_launch(void* const* d_in, const int* in_sizes, int n_in,
                              void* d_out, int out_size, void* d_ws, size_t ws_size,
                              hipStream_t stream) {
  const float* Q = (const float*)d_in[0];
  const float* K = (const float*)d_in[1];
  const float* V = (const float*)d_in[2];
  float* O = (float*)d_out;
  (void)in_sizes; (void)n_in; (void)out_size; (void)d_ws; (void)ws_size;
  dim3 grid(SEQ / 64, BATCH * NHQ);
  attn_fwd<<<grid, dim3(256), 0, stream>>>(Q, K, V, O);
}